// Round 9
// baseline (319.629 us; speedup 1.0000x reference)
//
#include <hip/hip_runtime.h>
#include <hip/hip_bf16.h>

#define NN 50000
#define EE 400000
#define GG 64
#define CAP 48
#define SPLIT 16

typedef unsigned short u16;
typedef unsigned char u8;
typedef __attribute__((ext_vector_type(8))) short bf16x8;
typedef __attribute__((ext_vector_type(4))) float f32x4;
typedef __attribute__((ext_vector_type(2))) float f32x2;

__device__ __forceinline__ float b2f(u16 u) {
    unsigned int x = ((unsigned int)u) << 16;
    return __uint_as_float(x);
}
__device__ __forceinline__ u16 f2b(float f) {
    unsigned int x = __float_as_uint(f);
    unsigned int r = x + 0x7fffu + ((x >> 16) & 1u);
    return (u16)(r >> 16);
}
// fp8 e4m3 (OCP) via HW converts — internal tensors h1, hL2 only.
__device__ __forceinline__ u8 f2fp8(float f) {
    return (u8)(__builtin_amdgcn_cvt_pk_fp8_f32(f, f, 0, false) & 0xFF);
}
__device__ __forceinline__ f32x2 fp8x2_f32(unsigned int v, bool hi) {
    return hi ? __builtin_amdgcn_cvt_pk_f32_fp8(v, true)
              : __builtin_amdgcn_cvt_pk_f32_fp8(v, false);
}
__device__ __forceinline__ float lrelu(float v) { return v > 0.f ? v : 0.2f * v; }

// ---- fused prep: init CSR + gstart + cvtW2 + prepW1 + zero pooled.
// grid 455: [0,196) init, 196 gstart, [197,453) cvtW2, 453 prepW1, 454 pooled.
__global__ void k_prep(const int* __restrict__ batch, int* __restrict__ deg,
                       int* __restrict__ col, int* __restrict__ gstart,
                       const float* __restrict__ W1, const float* __restrict__ as1,
                       const float* __restrict__ ad1, u16* __restrict__ W1p,
                       const float* __restrict__ W2, u16* __restrict__ W2p,
                       float* __restrict__ pooled) {
    __shared__ float asw[16][8];
    int b = blockIdx.x, t = threadIdx.x;
    if (b < 196) {
        int n = b * 256 + t;
        if (n < NN) { deg[n] = 1; col[(size_t)n * CAP] = n; }
    } else if (b == 196) {
        if (t <= GG) {
            int lo = 0, hi = NN;
            while (lo < hi) {
                int mid = (lo + hi) >> 1;
                if (batch[mid] < t) lo = mid + 1; else hi = mid;
            }
            gstart[t] = lo;
        }
    } else if (b < 453) {
        int idx = (b - 197) * 256 + t;   // 65536 total
        int j = idx & 7;
        int l = (idx >> 3) & 63;
        int ct = idx >> 9;
        int c = ct >> 3, tt = ct & 7;
        int k = c * 32 + (l >> 4) * 8 + j;
        int n = tt * 16 + (l & 15);
        W2p[idx] = f2b(W2[k * 128 + n]);
    } else if (b == 453) {
        if (t < 128) {
            int k = t >> 3, h = t & 7;
            int hd = h & 3;
            const float* att = (h >= 4) ? ad1 : as1;
            float s = 0.f;
            for (int c = 0; c < 128; c++) s += W1[k * 512 + hd * 128 + c] * att[hd * 128 + c];
            asw[k][h] = s;
        }
        __syncthreads();
        for (int idx = t; idx < 33 * 64 * 8; idx += 256) {
            int j = idx & 7, l = (idx >> 3) & 63, tt = idx >> 9;
            int quad = l >> 4, m = l & 15;
            int k = quad * 8 + j;
            float v = 0.f;
            if (k < 16) {
                if (tt < 32) v = W1[k * 512 + tt * 16 + m];
                else if (m < 8) v = asw[k][m];
            }
            W1p[idx] = f2b(v);
        }
    } else {
        for (int i = t; i < GG * 128; i += 256) pooled[i] = 0.f;
    }
}

// ---- bucket-append edges by dst
__global__ void k_edges(const int* __restrict__ ei, int* __restrict__ deg,
                        int* __restrict__ col) {
    int e = blockIdx.x * 256 + threadIdx.x;
    if (e < EE) {
        int s = ei[e];
        int d = ei[EE + e];
        int slot = atomicAdd(&deg[d], 1);
        if (slot < CAP) col[(size_t)d * CAP + slot] = s;
    }
}

// ---- layer1 linear via MFMA: [h1(fp8) | a_src1 | a_dst1] = x @ [W1 | asW]
__global__ __launch_bounds__(256) void k_gemm1(
    const float* __restrict__ x, const u16* __restrict__ W1p,
    u8* __restrict__ h1, float* __restrict__ a_src1, float* __restrict__ a_dst1) {
    int tid = threadIdx.x;
    int wave = tid >> 6, l = tid & 63;
    int quad = l >> 4, m = l & 15;
    int row0 = blockIdx.x * 64 + wave * 16;
    int arow = row0 + m;
    int arow_c = arow < NN ? arow : (NN - 1);
    bf16x8 af;
    if (quad < 2) {
        const float* xp = x + arow_c * 16 + quad * 8;
        float4 x0 = *(const float4*)(xp);
        float4 x1 = *(const float4*)(xp + 4);
        u16 tmp[8] = {f2b(x0.x), f2b(x0.y), f2b(x0.z), f2b(x0.w),
                      f2b(x1.x), f2b(x1.y), f2b(x1.z), f2b(x1.w)};
        af = *(bf16x8*)tmp;
    } else {
        af = (bf16x8){0, 0, 0, 0, 0, 0, 0, 0};
    }
    const u16* bp = W1p + l * 8;
    f32x4 acc[33];
    #pragma unroll
    for (int tt = 0; tt < 33; tt++) acc[tt] = (f32x4){0.f, 0.f, 0.f, 0.f};
    #pragma unroll
    for (int tt = 0; tt < 33; tt++) {
        bf16x8 bf = *(const bf16x8*)(bp + (size_t)tt * 512);
        acc[tt] = __builtin_amdgcn_mfma_f32_16x16x32_bf16(af, bf, acc[tt], 0, 0, 0);
    }
    #pragma unroll
    for (int r = 0; r < 4; r++) {
        int row = row0 + quad * 4 + r;
        if (row >= NN) continue;
        #pragma unroll
        for (int tt = 0; tt < 32; tt++)
            h1[(size_t)row * 512 + tt * 16 + m] = f2fp8(acc[tt][r]);
        float v = acc[32][r];
        if (m < 4) a_src1[row * 4 + m] = v;
        else if (m < 8) a_dst1[row * 4 + (m - 4)] = v;
    }
}

// ---- layer1 softmax weights: thread = (node, head). Two passes, no shuffles.
// alpha1[(n*CAP+j)*4+h] = bf16 normalized weight.
__global__ void k_alpha1(const int* __restrict__ deg, const int* __restrict__ col,
                         const float* __restrict__ a_src1, const float* __restrict__ a_dst1,
                         u16* __restrict__ alpha1) {
    int tid = blockIdx.x * 256 + threadIdx.x;
    int n = tid >> 2, h = tid & 3;
    if (n >= NN) return;
    int dg = min(deg[n], CAP);
    float ad = a_dst1[n * 4 + h];
    const int* cp = col + (size_t)n * CAP;
    float sum = 0.f;
    for (int j = 0; j < dg; j++) {
        int s = cp[j];
        sum += __expf(lrelu(a_src1[s * 4 + h] + ad));
    }
    float inv = 1.0f / sum;
    u16* ap = alpha1 + (size_t)n * CAP * 4 + h;
    for (int j = 0; j < dg; j++) {
        int s = cp[j];
        float e = __expf(lrelu(a_src1[s * 4 + h] + ad));
        ap[j * 4] = f2b(e * inv);
    }
}

// ---- layer1 aggregation: WAVE-PER-NODE, lane owns 8 full-row channels.
// 2 rows/iter; indices broadcast via shfl (scalar addr); alphas from global.
__global__ __launch_bounds__(256) void k_agg1(
    const int* __restrict__ deg, const int* __restrict__ col,
    const u16* __restrict__ alpha1, const u8* __restrict__ h1,
    const float* __restrict__ b1, u16* __restrict__ h2pre) {
    int t = threadIdx.x;
    int wave = t >> 6, l = t & 63;
    int n = blockIdx.x * 4 + wave;
    if (n >= NN) return;
    int dg = min(deg[n], CAP);
    int sl = (l < dg) ? col[(size_t)n * CAP + l] : 0;
    int h = l >> 4;                       // head of this lane's channel slice
    const u8* hb = h1 + l * 8;
    const u16* ap = alpha1 + (size_t)n * CAP * 4 + h;
    f32x2 acc[4] = {{0.f, 0.f}, {0.f, 0.f}, {0.f, 0.f}, {0.f, 0.f}};
    int iters = (dg + 1) >> 1;
    for (int j = 0; j < iters; j++) {
        int eA = 2 * j, eB = 2 * j + 1;
        int sA = __shfl(sl, eA);
        int sB = __shfl(sl, eB);
        float aA = b2f(ap[eA * 4]);
        float aB = (eB < dg) ? b2f(ap[eB * 4]) : 0.f;
        uint2 uA = *(const uint2*)(hb + (size_t)sA * 512);
        uint2 uB = *(const uint2*)(hb + (size_t)sB * 512);
        acc[0] += aA * fp8x2_f32(uA.x, false);
        acc[1] += aA * fp8x2_f32(uA.x, true);
        acc[2] += aA * fp8x2_f32(uA.y, false);
        acc[3] += aA * fp8x2_f32(uA.y, true);
        acc[0] += aB * fp8x2_f32(uB.x, false);
        acc[1] += aB * fp8x2_f32(uB.x, true);
        acc[2] += aB * fp8x2_f32(uB.y, false);
        acc[3] += aB * fp8x2_f32(uB.y, true);
    }
    int ch0 = l * 8;
    float4 bA = *(const float4*)(b1 + ch0);
    float4 bB = *(const float4*)(b1 + ch0 + 4);
    float av[8] = {acc[0].x, acc[0].y, acc[1].x, acc[1].y,
                   acc[2].x, acc[2].y, acc[3].x, acc[3].y};
    float bb[8] = {bA.x, bA.y, bA.z, bA.w, bB.x, bB.y, bB.z, bB.w};
    u16 ov[8];
    #pragma unroll
    for (int k = 0; k < 8; k++) {
        float v = av[k] + bb[k];
        v = v > 0.f ? v : __expf(v) - 1.0f;
        ov[k] = f2b(v);
    }
    *(bf16x8*)(h2pre + (size_t)n * 512 + ch0) = *(bf16x8*)ov;
}

// ---- layer2 linear via MFMA: hL2(fp8) = h2pre@W2, fused a_src2/a_dst2.
__global__ __launch_bounds__(256) void k_gemm2(
    const u16* __restrict__ h2pre, const u16* __restrict__ W2p,
    const float* __restrict__ as2, const float* __restrict__ ad2,
    u8* __restrict__ hL2, float* __restrict__ a_src2, float* __restrict__ a_dst2) {
    int t = threadIdx.x;
    int wave = t >> 6, l = t & 63;
    int quad = l >> 4, m = l & 15;
    int row0 = blockIdx.x * 64 + wave * 16;
    int arow = row0 + m;
    int arow_c = arow < NN ? arow : (NN - 1);
    const u16* aptr = h2pre + (size_t)arow_c * 512 + quad * 8;
    const u16* bptr = W2p + l * 8;
    f32x4 acc[8];
    #pragma unroll
    for (int tt = 0; tt < 8; tt++) acc[tt] = (f32x4){0.f, 0.f, 0.f, 0.f};
    for (int c = 0; c < 16; c++) {
        bf16x8 af = *(const bf16x8*)(aptr + c * 32);
        #pragma unroll
        for (int tt = 0; tt < 8; tt++) {
            bf16x8 bf = *(const bf16x8*)(bptr + (size_t)(c * 8 + tt) * 512);
            acc[tt] = __builtin_amdgcn_mfma_f32_16x16x32_bf16(af, bf, acc[tt], 0, 0, 0);
        }
    }
    float asv[8], adv[8];
    #pragma unroll
    for (int tt = 0; tt < 8; tt++) {
        int colc = tt * 16 + m;
        asv[tt] = as2[colc];
        adv[tt] = ad2[colc];
    }
    #pragma unroll
    for (int r = 0; r < 4; r++) {
        int row = row0 + quad * 4 + r;
        bool ok = row < NN;
        float rs = 0.f, rd = 0.f;
        #pragma unroll
        for (int tt = 0; tt < 8; tt++) {
            float v = acc[tt][r];
            if (ok) hL2[(size_t)row * 128 + tt * 16 + m] = f2fp8(v);
            rs += v * asv[tt];
            rd += v * adv[tt];
        }
        #pragma unroll
        for (int o = 1; o < 16; o <<= 1) {
            rs += __shfl_xor(rs, o, 64);
            rd += __shfl_xor(rd, o, 64);
        }
        if (ok && m == 0) { a_src2[row] = rs; a_dst2[row] = rd; }
    }
}

// ---- layer2 softmax weights: thread = node (1 head).
__global__ void k_alpha2(const int* __restrict__ deg, const int* __restrict__ col,
                         const float* __restrict__ a_src2, const float* __restrict__ a_dst2,
                         u16* __restrict__ alpha2) {
    int n = blockIdx.x * 256 + threadIdx.x;
    if (n >= NN) return;
    int dg = min(deg[n], CAP);
    float ad = a_dst2[n];
    const int* cp = col + (size_t)n * CAP;
    float sum = 0.f;
    for (int j = 0; j < dg; j++)
        sum += __expf(lrelu(a_src2[cp[j]] + ad));
    float inv = 1.0f / sum;
    u16* ap = alpha2 + (size_t)n * CAP;
    for (int j = 0; j < dg; j++) {
        float e = __expf(lrelu(a_src2[cp[j]] + ad));
        ap[j] = f2b(e * inv);
    }
}

// ---- layer2 aggregation: WAVE-PER-NODE, lane owns 2 channels, 2 rows/iter.
__global__ __launch_bounds__(256) void k_agg2(
    const int* __restrict__ deg, const int* __restrict__ col,
    const u16* __restrict__ alpha2, const u8* __restrict__ hL2,
    const float* __restrict__ b2v, float* __restrict__ hfin) {
    int t = threadIdx.x;
    int wave = t >> 6, l = t & 63;
    int n = blockIdx.x * 4 + wave;
    if (n >= NN) return;
    int dg = min(deg[n], CAP);
    int sl = (l < dg) ? col[(size_t)n * CAP + l] : 0;
    const u8* hb = hL2 + l * 2;
    const u16* ap = alpha2 + (size_t)n * CAP;
    f32x2 acc = {0.f, 0.f};
    int iters = (dg + 1) >> 1;
    for (int j = 0; j < iters; j++) {
        int eA = 2 * j, eB = 2 * j + 1;
        int sA = __shfl(sl, eA);
        int sB = __shfl(sl, eB);
        float aA = b2f(ap[eA]);
        float aB = (eB < dg) ? b2f(ap[eB]) : 0.f;
        unsigned int uA = *(const u16*)(hb + (size_t)sA * 128);
        unsigned int uB = *(const u16*)(hb + (size_t)sB * 128);
        acc += aA * fp8x2_f32(uA, false);
        acc += aB * fp8x2_f32(uB, false);
    }
    float o0 = acc.x + b2v[2 * l];     o0 = o0 > 0.f ? o0 : __expf(o0) - 1.0f;
    float o1 = acc.y + b2v[2 * l + 1]; o1 = o1 > 0.f ? o1 : __expf(o1) - 1.0f;
    float2 ov; ov.x = o0; ov.y = o1;
    *(float2*)(hfin + (size_t)n * 128 + 2 * l) = ov;
}

// ---- parallel mean-pool partials
__global__ __launch_bounds__(128) void k_pool(
    const int* __restrict__ gstart, const float* __restrict__ hfin,
    float* __restrict__ pooled) {
    int g = blockIdx.x / SPLIT, i = blockIdx.x % SPLIT, t = threadIdx.x;
    int s0 = gstart[g], s1 = gstart[g + 1];
    int len = s1 - s0;
    int chunk = (len + SPLIT - 1) / SPLIT;
    int a = s0 + i * chunk;
    int b = min(a + chunk, s1);
    if (a >= b) return;
    float acc = 0.f;
    for (int n = a; n < b; n++) acc += hfin[(size_t)n * 128 + t];
    atomicAdd(&pooled[g * 128 + t], acc);
}

// ---- graph MLP + classifier
__global__ __launch_bounds__(128) void k_head(
    const int* __restrict__ gstart, const float* __restrict__ pooled,
    const float* __restrict__ gfeat,
    const float* __restrict__ Wg1, const float* __restrict__ bg1,
    const float* __restrict__ Wg2, const float* __restrict__ bg2,
    const float* __restrict__ Wc1, const float* __restrict__ bc1,
    const float* __restrict__ Wc2, const float* __restrict__ bc2,
    float* __restrict__ out) {
    __shared__ float z[160];
    __shared__ float hg[32];
    __shared__ float c1b[128];
    int g = blockIdx.x, t = threadIdx.x;
    float cntf = (float)(gstart[g + 1] - gstart[g]);
    z[t] = pooled[g * 128 + t] / fmaxf(cntf, 1.0f);
    if (t < 32) {
        float a = bg1[t];
        for (int i = 0; i < 10; i++) a += gfeat[g * 10 + i] * Wg1[i * 32 + t];
        hg[t] = fmaxf(a, 0.f);
    }
    __syncthreads();
    if (t < 32) {
        float a = bg2[t];
        for (int i = 0; i < 32; i++) a += hg[i] * Wg2[i * 32 + t];
        z[128 + t] = a;
    }
    __syncthreads();
    float a = bc1[t];
    for (int i = 0; i < 160; i++) a += z[i] * Wc1[i * 128 + t];
    c1b[t] = fmaxf(a, 0.f);
    __syncthreads();
    if (t < 6) {
        float o = bc2[t];
        for (int i = 0; i < 128; i++) o += c1b[i] * Wc2[i * 6 + t];
        out[g * 6 + t] = o;
    }
}

extern "C" void kernel_launch(void* const* d_in, const int* in_sizes, int n_in,
                              void* d_out, int out_size, void* d_ws, size_t ws_size,
                              hipStream_t stream) {
    const float* x     = (const float*)d_in[0];
    const int*   ei    = (const int*)d_in[1];
    const int*   batch = (const int*)d_in[2];
    const float* gfeat = (const float*)d_in[3];
    const float* W1    = (const float*)d_in[4];
    const float* as1   = (const float*)d_in[5];
    const float* ad1   = (const float*)d_in[6];
    const float* b1    = (const float*)d_in[7];
    const float* W2    = (const float*)d_in[8];
    const float* as2   = (const float*)d_in[9];
    const float* ad2   = (const float*)d_in[10];
    const float* b2    = (const float*)d_in[11];
    const float* Wg1   = (const float*)d_in[12];
    const float* bg1   = (const float*)d_in[13];
    const float* Wg2   = (const float*)d_in[14];
    const float* bg2   = (const float*)d_in[15];
    const float* Wc1   = (const float*)d_in[16];
    const float* bc1   = (const float*)d_in[17];
    const float* Wc2   = (const float*)d_in[18];
    const float* bc2   = (const float*)d_in[19];
    float* out = (float*)d_out;

    size_t off = 0;
    char* base = (char*)d_ws;
    auto take = [&](size_t nbytes) -> char* {
        char* p = base + off;
        off = (off + nbytes + 255) & ~(size_t)255;
        return p;
    };
    u8*    h1     = (u8*)take((size_t)NN * 512);
    u16*   h2pre  = (u16*)take((size_t)NN * 512 * 2);
    u8*    hL2    = (u8*)take((size_t)NN * 128);
    float* hfin   = (float*)take((size_t)NN * 128 * 4);
    float* a_src1 = (float*)take((size_t)NN * 4 * 4);
    float* a_dst1 = (float*)take((size_t)NN * 4 * 4);
    float* a_src2 = (float*)take((size_t)NN * 4);
    float* a_dst2 = (float*)take((size_t)NN * 4);
    int*   deg    = (int*)take((size_t)NN * 4);
    int*   col    = (int*)take((size_t)NN * CAP * 4);
    u16*   alpha1 = (u16*)take((size_t)NN * CAP * 4 * 2);
    u16*   alpha2 = (u16*)take((size_t)NN * CAP * 2);
    float* pooled = (float*)take(GG * 128 * 4);
    int*   gstart = (int*)take((GG + 1) * 4);
    u16*   W2p    = (u16*)take((size_t)512 * 128 * 2);
    u16*   W1p    = (u16*)take((size_t)33 * 64 * 8 * 2);
    (void)ws_size; (void)in_sizes; (void)n_in; (void)out_size;

    k_prep<<<455, 256, 0, stream>>>(batch, deg, col, gstart, W1, as1, ad1, W1p,
                                    W2, W2p, pooled);
    k_edges<<<(EE + 255) / 256, 256, 0, stream>>>(ei, deg, col);
    k_gemm1<<<(NN + 63) / 64, 256, 0, stream>>>(x, W1p, h1, a_src1, a_dst1);
    k_alpha1<<<(NN * 4 + 255) / 256, 256, 0, stream>>>(deg, col, a_src1, a_dst1, alpha1);
    k_agg1<<<(NN + 3) / 4, 256, 0, stream>>>(deg, col, alpha1, h1, b1, h2pre);
    k_gemm2<<<(NN + 63) / 64, 256, 0, stream>>>(h2pre, W2p, as2, ad2, hL2, a_src2, a_dst2);
    k_alpha2<<<(NN + 255) / 256, 256, 0, stream>>>(deg, col, a_src2, a_dst2, alpha2);
    k_agg2<<<(NN + 3) / 4, 256, 0, stream>>>(deg, col, alpha2, hL2, b2, hfin);
    k_pool<<<GG * SPLIT, 128, 0, stream>>>(gstart, hfin, pooled);
    k_head<<<GG, 128, 0, stream>>>(gstart, pooled, gfeat, Wg1, bg1, Wg2, bg2,
                                   Wc1, bc1, Wc2, bc2, out);
}

// Round 10
// 268.331 us; speedup vs baseline: 1.1912x; 1.1912x over previous
//
#include <hip/hip_runtime.h>
#include <hip/hip_bf16.h>

#define NN 50000
#define EE 400000
#define GG 64
#define CAP 48

typedef unsigned short u16;
typedef unsigned char u8;
typedef __attribute__((ext_vector_type(8))) short bf16x8;
typedef __attribute__((ext_vector_type(4))) float f32x4;
typedef __attribute__((ext_vector_type(2))) float f32x2;

__device__ __forceinline__ float b2f(u16 u) {
    unsigned int x = ((unsigned int)u) << 16;
    return __uint_as_float(x);
}
__device__ __forceinline__ u16 f2b(float f) {
    unsigned int x = __float_as_uint(f);
    unsigned int r = x + 0x7fffu + ((x >> 16) & 1u);
    return (u16)(r >> 16);
}
// fp8 e4m3 (OCP) via HW converts — internal tensors h1, hL2 only.
__device__ __forceinline__ u8 f2fp8(float f) {
    return (u8)(__builtin_amdgcn_cvt_pk_fp8_f32(f, f, 0, false) & 0xFF);
}
__device__ __forceinline__ f32x2 fp8x2_f32(unsigned int v, bool hi) {
    return hi ? __builtin_amdgcn_cvt_pk_f32_fp8(v, true)
              : __builtin_amdgcn_cvt_pk_f32_fp8(v, false);
}
__device__ __forceinline__ float wred_sum(float v) {
    #pragma unroll
    for (int o = 32; o; o >>= 1) v += __shfl_xor(v, o, 64);
    return v;
}
__device__ __forceinline__ float lrelu(float v) { return v > 0.f ? v : 0.2f * v; }

// ---- fused prep: init CSR + gstart + cvtW2 + prepW1 + zero pooled.
// grid 455: [0,196) init, 196 gstart, [197,453) cvtW2, 453 prepW1, 454 pooled.
__global__ void k_prep(const int* __restrict__ batch, int* __restrict__ deg,
                       int* __restrict__ col, int* __restrict__ gstart,
                       const float* __restrict__ W1, const float* __restrict__ as1,
                       const float* __restrict__ ad1, u16* __restrict__ W1p,
                       const float* __restrict__ W2, u16* __restrict__ W2p,
                       float* __restrict__ pooled) {
    __shared__ float asw[16][8];
    int b = blockIdx.x, t = threadIdx.x;
    if (b < 196) {
        int n = b * 256 + t;
        if (n < NN) { deg[n] = 1; col[(size_t)n * CAP] = n; }
    } else if (b == 196) {
        if (t <= GG) {
            int lo = 0, hi = NN;
            while (lo < hi) {
                int mid = (lo + hi) >> 1;
                if (batch[mid] < t) lo = mid + 1; else hi = mid;
            }
            gstart[t] = lo;
        }
    } else if (b < 453) {
        int idx = (b - 197) * 256 + t;   // 65536 total
        int j = idx & 7;
        int l = (idx >> 3) & 63;
        int ct = idx >> 9;
        int c = ct >> 3, tt = ct & 7;
        int k = c * 32 + (l >> 4) * 8 + j;
        int n = tt * 16 + (l & 15);
        W2p[idx] = f2b(W2[k * 128 + n]);
    } else if (b == 453) {
        // asw: 128 dots of length 128, 2 threads per dot (parallelized)
        int pair = t >> 1, half = t & 1;
        int k = pair >> 3, h = pair & 7;
        int hd = h & 3;
        const float* att = (h >= 4) ? ad1 : as1;
        float s = 0.f;
        int c0 = half * 64;
        for (int c = c0; c < c0 + 64; c++)
            s += W1[k * 512 + hd * 128 + c] * att[hd * 128 + c];
        s += __shfl_xor(s, 1, 64);
        if (half == 0) asw[k][h] = s;
        __syncthreads();
        for (int idx = t; idx < 33 * 64 * 8; idx += 256) {
            int j = idx & 7, l = (idx >> 3) & 63, tt = idx >> 9;
            int quad = l >> 4, m = l & 15;
            int k2 = quad * 8 + j;
            float v = 0.f;
            if (k2 < 16) {
                if (tt < 32) v = W1[k2 * 512 + tt * 16 + m];
                else if (m < 8) v = asw[k2][m];
            }
            W1p[idx] = f2b(v);
        }
    } else {
        for (int i = t; i < GG * 128; i += 256) pooled[i] = 0.f;
    }
}

// ---- bucket-append edges by dst
__global__ void k_edges(const int* __restrict__ ei, int* __restrict__ deg,
                        int* __restrict__ col) {
    int e = blockIdx.x * 256 + threadIdx.x;
    if (e < EE) {
        int s = ei[e];
        int d = ei[EE + e];
        int slot = atomicAdd(&deg[d], 1);
        if (slot < CAP) col[(size_t)d * CAP + slot] = s;
    }
}

// ---- layer1 linear via MFMA: [h1(fp8) | a_src1 | a_dst1] = x @ [W1 | asW]
__global__ __launch_bounds__(256) void k_gemm1(
    const float* __restrict__ x, const u16* __restrict__ W1p,
    u8* __restrict__ h1, float* __restrict__ a_src1, float* __restrict__ a_dst1) {
    int tid = threadIdx.x;
    int wave = tid >> 6, l = tid & 63;
    int quad = l >> 4, m = l & 15;
    int row0 = blockIdx.x * 64 + wave * 16;
    int arow = row0 + m;
    int arow_c = arow < NN ? arow : (NN - 1);
    bf16x8 af;
    if (quad < 2) {
        const float* xp = x + arow_c * 16 + quad * 8;
        float4 x0 = *(const float4*)(xp);
        float4 x1 = *(const float4*)(xp + 4);
        u16 tmp[8] = {f2b(x0.x), f2b(x0.y), f2b(x0.z), f2b(x0.w),
                      f2b(x1.x), f2b(x1.y), f2b(x1.z), f2b(x1.w)};
        af = *(bf16x8*)tmp;
    } else {
        af = (bf16x8){0, 0, 0, 0, 0, 0, 0, 0};
    }
    const u16* bp = W1p + l * 8;
    f32x4 acc[33];
    #pragma unroll
    for (int tt = 0; tt < 33; tt++) acc[tt] = (f32x4){0.f, 0.f, 0.f, 0.f};
    #pragma unroll
    for (int tt = 0; tt < 33; tt++) {
        bf16x8 bf = *(const bf16x8*)(bp + (size_t)tt * 512);
        acc[tt] = __builtin_amdgcn_mfma_f32_16x16x32_bf16(af, bf, acc[tt], 0, 0, 0);
    }
    #pragma unroll
    for (int r = 0; r < 4; r++) {
        int row = row0 + quad * 4 + r;
        if (row >= NN) continue;
        #pragma unroll
        for (int tt = 0; tt < 32; tt++)
            h1[(size_t)row * 512 + tt * 16 + m] = f2fp8(acc[tt][r]);
        float v = acc[32][r];
        if (m < 4) a_src1[row * 4 + m] = v;
        else if (m < 8) a_dst1[row * 4 + (m - 4)] = v;
    }
}

// ---- layer1 attention + aggregation: WAVE-PER-NODE, fused softmax.
// CAP=48 <= 64: one lane-slot covers all edges. Alpha computed in-wave,
// parked in LDS (same-wave write->read, no barrier). Lean 2-rows/iter loop.
__global__ __launch_bounds__(256) void k_agg1(
    const int* __restrict__ deg, const int* __restrict__ col,
    const float* __restrict__ a_src1, const float* __restrict__ a_dst1,
    const u8* __restrict__ h1, const float* __restrict__ b1,
    u16* __restrict__ h2pre) {
    __shared__ float alphaS[4][CAP][4];
    int t = threadIdx.x;
    int wave = t >> 6, l = t & 63;
    int n = blockIdx.x * 4 + wave;
    if (n >= NN) return;
    int dg = min(deg[n], CAP);
    int sl = (l < dg) ? col[(size_t)n * CAP + l] : 0;
    // softmax prologue (single slot)
    float4 ad = *(const float4*)(a_dst1 + n * 4);
    float4 as = *(const float4*)(a_src1 + (size_t)sl * 4);
    float4 e;
    e.x = __expf(lrelu(as.x + ad.x)); e.y = __expf(lrelu(as.y + ad.y));
    e.z = __expf(lrelu(as.z + ad.z)); e.w = __expf(lrelu(as.w + ad.w));
    if (l >= dg) e = (float4){0.f, 0.f, 0.f, 0.f};
    float4 inv;
    inv.x = 1.0f / wred_sum(e.x);
    inv.y = 1.0f / wred_sum(e.y);
    inv.z = 1.0f / wred_sum(e.z);
    inv.w = 1.0f / wred_sum(e.w);
    if (l < dg) {
        float4 a4;
        a4.x = e.x * inv.x; a4.y = e.y * inv.y;
        a4.z = e.z * inv.z; a4.w = e.w * inv.w;
        *(float4*)&alphaS[wave][l][0] = a4;
    }
    int h = l >> 4;                       // head of this lane's channel slice
    const u8* hb = h1 + l * 8;
    f32x2 acc[4] = {{0.f, 0.f}, {0.f, 0.f}, {0.f, 0.f}, {0.f, 0.f}};
    int iters = (dg + 1) >> 1;
    for (int j = 0; j < iters; j++) {
        int eA = 2 * j, eB = 2 * j + 1;
        int sA = __shfl(sl, eA);
        int sB = __shfl(sl, eB);
        float aA = alphaS[wave][eA][h];
        float aB = (eB < dg) ? alphaS[wave][eB][h] : 0.f;
        uint2 uA = *(const uint2*)(hb + (size_t)sA * 512);
        uint2 uB = *(const uint2*)(hb + (size_t)sB * 512);
        acc[0] += aA * fp8x2_f32(uA.x, false);
        acc[1] += aA * fp8x2_f32(uA.x, true);
        acc[2] += aA * fp8x2_f32(uA.y, false);
        acc[3] += aA * fp8x2_f32(uA.y, true);
        acc[0] += aB * fp8x2_f32(uB.x, false);
        acc[1] += aB * fp8x2_f32(uB.x, true);
        acc[2] += aB * fp8x2_f32(uB.y, false);
        acc[3] += aB * fp8x2_f32(uB.y, true);
    }
    int ch0 = l * 8;
    float4 bA = *(const float4*)(b1 + ch0);
    float4 bB = *(const float4*)(b1 + ch0 + 4);
    float av[8] = {acc[0].x, acc[0].y, acc[1].x, acc[1].y,
                   acc[2].x, acc[2].y, acc[3].x, acc[3].y};
    float bb[8] = {bA.x, bA.y, bA.z, bA.w, bB.x, bB.y, bB.z, bB.w};
    u16 ov[8];
    #pragma unroll
    for (int k = 0; k < 8; k++) {
        float v = av[k] + bb[k];
        v = v > 0.f ? v : __expf(v) - 1.0f;
        ov[k] = f2b(v);
    }
    *(bf16x8*)(h2pre + (size_t)n * 512 + ch0) = *(bf16x8*)ov;
}

// ---- layer2 linear via MFMA: hL2(fp8) = h2pre@W2, fused a_src2/a_dst2.
__global__ __launch_bounds__(256) void k_gemm2(
    const u16* __restrict__ h2pre, const u16* __restrict__ W2p,
    const float* __restrict__ as2, const float* __restrict__ ad2,
    u8* __restrict__ hL2, float* __restrict__ a_src2, float* __restrict__ a_dst2) {
    int t = threadIdx.x;
    int wave = t >> 6, l = t & 63;
    int quad = l >> 4, m = l & 15;
    int row0 = blockIdx.x * 64 + wave * 16;
    int arow = row0 + m;
    int arow_c = arow < NN ? arow : (NN - 1);
    const u16* aptr = h2pre + (size_t)arow_c * 512 + quad * 8;
    const u16* bptr = W2p + l * 8;
    f32x4 acc[8];
    #pragma unroll
    for (int tt = 0; tt < 8; tt++) acc[tt] = (f32x4){0.f, 0.f, 0.f, 0.f};
    for (int c = 0; c < 16; c++) {
        bf16x8 af = *(const bf16x8*)(aptr + c * 32);
        #pragma unroll
        for (int tt = 0; tt < 8; tt++) {
            bf16x8 bf = *(const bf16x8*)(bptr + (size_t)(c * 8 + tt) * 512);
            acc[tt] = __builtin_amdgcn_mfma_f32_16x16x32_bf16(af, bf, acc[tt], 0, 0, 0);
        }
    }
    float asv[8], adv[8];
    #pragma unroll
    for (int tt = 0; tt < 8; tt++) {
        int colc = tt * 16 + m;
        asv[tt] = as2[colc];
        adv[tt] = ad2[colc];
    }
    #pragma unroll
    for (int r = 0; r < 4; r++) {
        int row = row0 + quad * 4 + r;
        bool ok = row < NN;
        float rs = 0.f, rd = 0.f;
        #pragma unroll
        for (int tt = 0; tt < 8; tt++) {
            float v = acc[tt][r];
            if (ok) hL2[(size_t)row * 128 + tt * 16 + m] = f2fp8(v);
            rs += v * asv[tt];
            rd += v * adv[tt];
        }
        #pragma unroll
        for (int o = 1; o < 16; o <<= 1) {
            rs += __shfl_xor(rs, o, 64);
            rd += __shfl_xor(rd, o, 64);
        }
        if (ok && m == 0) { a_src2[row] = rs; a_dst2[row] = rd; }
    }
}

// ---- layer2 attention + aggregation + POOL: WAVE-PER-NODE, fused softmax,
// block-combined atomicAdd into pooled (batch sorted -> 4 nodes almost
// always share a graph; fallback handles boundaries).
__global__ __launch_bounds__(256) void k_agg2(
    const int* __restrict__ deg, const int* __restrict__ col,
    const float* __restrict__ a_src2, const float* __restrict__ a_dst2,
    const u8* __restrict__ hL2, const float* __restrict__ b2v,
    const int* __restrict__ batch, float* __restrict__ pooled) {
    __shared__ float red[4][128];
    __shared__ int gS[4];
    int t = threadIdx.x;
    int wave = t >> 6, l = t & 63;
    int n = blockIdx.x * 4 + wave;
    if (n >= NN) return;
    int dg = min(deg[n], CAP);
    int sl = (l < dg) ? col[(size_t)n * CAP + l] : 0;
    float ad = a_dst2[n];
    float e = (l < dg) ? __expf(lrelu(a_src2[sl] + ad)) : 0.f;
    float inv = 1.0f / wred_sum(e);
    float al = e * inv;                   // lane's own alpha (0 beyond dg)
    f32x2 acc = {0.f, 0.f};
    const u8* hb = hL2 + l * 2;
    int iters = (dg + 1) >> 1;
    for (int j = 0; j < iters; j++) {
        int eA = 2 * j, eB = 2 * j + 1;
        int sA = __shfl(sl, eA);
        int sB = __shfl(sl, eB);
        float aA = __shfl(al, eA);
        float aB = __shfl(al, eB);
        unsigned int uA = *(const u16*)(hb + (size_t)sA * 128);
        unsigned int uB = *(const u16*)(hb + (size_t)sB * 128);
        acc += aA * fp8x2_f32(uA, false);
        acc += aB * fp8x2_f32(uB, false);
    }
    float o0 = acc.x + b2v[2 * l];     o0 = o0 > 0.f ? o0 : __expf(o0) - 1.0f;
    float o1 = acc.y + b2v[2 * l + 1]; o1 = o1 > 0.f ? o1 : __expf(o1) - 1.0f;
    red[wave][2 * l] = o0;
    red[wave][2 * l + 1] = o1;
    if (l == 0) gS[wave] = batch[n];
    __syncthreads();
    if (t < 128) {
        int g0 = gS[0];
        if (gS[1] == g0 && gS[2] == g0 && gS[3] == g0) {
            float s = red[0][t] + red[1][t] + red[2][t] + red[3][t];
            atomicAdd(&pooled[g0 * 128 + t], s);
        } else {
            #pragma unroll
            for (int w = 0; w < 4; w++)
                atomicAdd(&pooled[gS[w] * 128 + t], red[w][t]);
        }
    }
}

// ---- graph MLP + classifier (pooled holds per-graph SUMS)
__global__ __launch_bounds__(128) void k_head(
    const int* __restrict__ gstart, const float* __restrict__ pooled,
    const float* __restrict__ gfeat,
    const float* __restrict__ Wg1, const float* __restrict__ bg1,
    const float* __restrict__ Wg2, const float* __restrict__ bg2,
    const float* __restrict__ Wc1, const float* __restrict__ bc1,
    const float* __restrict__ Wc2, const float* __restrict__ bc2,
    float* __restrict__ out) {
    __shared__ float z[160];
    __shared__ float hg[32];
    __shared__ float c1b[128];
    int g = blockIdx.x, t = threadIdx.x;
    float cntf = (float)(gstart[g + 1] - gstart[g]);
    z[t] = pooled[g * 128 + t] / fmaxf(cntf, 1.0f);
    if (t < 32) {
        float a = bg1[t];
        for (int i = 0; i < 10; i++) a += gfeat[g * 10 + i] * Wg1[i * 32 + t];
        hg[t] = fmaxf(a, 0.f);
    }
    __syncthreads();
    if (t < 32) {
        float a = bg2[t];
        for (int i = 0; i < 32; i++) a += hg[i] * Wg2[i * 32 + t];
        z[128 + t] = a;
    }
    __syncthreads();
    float a = bc1[t];
    for (int i = 0; i < 160; i++) a += z[i] * Wc1[i * 128 + t];
    c1b[t] = fmaxf(a, 0.f);
    __syncthreads();
    if (t < 6) {
        float o = bc2[t];
        for (int i = 0; i < 128; i++) o += c1b[i] * Wc2[i * 6 + t];
        out[g * 6 + t] = o;
    }
}

extern "C" void kernel_launch(void* const* d_in, const int* in_sizes, int n_in,
                              void* d_out, int out_size, void* d_ws, size_t ws_size,
                              hipStream_t stream) {
    const float* x     = (const float*)d_in[0];
    const int*   ei    = (const int*)d_in[1];
    const int*   batch = (const int*)d_in[2];
    const float* gfeat = (const float*)d_in[3];
    const float* W1    = (const float*)d_in[4];
    const float* as1   = (const float*)d_in[5];
    const float* ad1   = (const float*)d_in[6];
    const float* b1    = (const float*)d_in[7];
    const float* W2    = (const float*)d_in[8];
    const float* as2   = (const float*)d_in[9];
    const float* ad2   = (const float*)d_in[10];
    const float* b2    = (const float*)d_in[11];
    const float* Wg1   = (const float*)d_in[12];
    const float* bg1   = (const float*)d_in[13];
    const float* Wg2   = (const float*)d_in[14];
    const float* bg2   = (const float*)d_in[15];
    const float* Wc1   = (const float*)d_in[16];
    const float* bc1   = (const float*)d_in[17];
    const float* Wc2   = (const float*)d_in[18];
    const float* bc2   = (const float*)d_in[19];
    float* out = (float*)d_out;

    size_t off = 0;
    char* base = (char*)d_ws;
    auto take = [&](size_t nbytes) -> char* {
        char* p = base + off;
        off = (off + nbytes + 255) & ~(size_t)255;
        return p;
    };
    u8*    h1     = (u8*)take((size_t)NN * 512);
    u16*   h2pre  = (u16*)take((size_t)NN * 512 * 2);
    u8*    hL2    = (u8*)take((size_t)NN * 128);
    float* a_src1 = (float*)take((size_t)NN * 4 * 4);
    float* a_dst1 = (float*)take((size_t)NN * 4 * 4);
    float* a_src2 = (float*)take((size_t)NN * 4);
    float* a_dst2 = (float*)take((size_t)NN * 4);
    int*   deg    = (int*)take((size_t)NN * 4);
    int*   col    = (int*)take((size_t)NN * CAP * 4);
    float* pooled = (float*)take(GG * 128 * 4);
    int*   gstart = (int*)take((GG + 1) * 4);
    u16*   W2p    = (u16*)take((size_t)512 * 128 * 2);
    u16*   W1p    = (u16*)take((size_t)33 * 64 * 8 * 2);
    (void)ws_size; (void)in_sizes; (void)n_in; (void)out_size;

    k_prep<<<455, 256, 0, stream>>>(batch, deg, col, gstart, W1, as1, ad1, W1p,
                                    W2, W2p, pooled);
    k_edges<<<(EE + 255) / 256, 256, 0, stream>>>(ei, deg, col);
    k_gemm1<<<(NN + 63) / 64, 256, 0, stream>>>(x, W1p, h1, a_src1, a_dst1);
    k_agg1<<<(NN + 3) / 4, 256, 0, stream>>>(deg, col, a_src1, a_dst1, h1, b1, h2pre);
    k_gemm2<<<(NN + 63) / 64, 256, 0, stream>>>(h2pre, W2p, as2, ad2, hL2, a_src2, a_dst2);
    k_agg2<<<(NN + 3) / 4, 256, 0, stream>>>(deg, col, a_src2, a_dst2, hL2, b2,
                                             batch, pooled);
    k_head<<<GG, 128, 0, stream>>>(gstart, pooled, gfeat, Wg1, bg1, Wg2, bg2,
                                   Wc1, bc1, Wc2, bc2, out);
}

// Round 11
// 256.568 us; speedup vs baseline: 1.2458x; 1.0459x over previous
//
#include <hip/hip_runtime.h>
#include <hip/hip_bf16.h>

#define NN 50000
#define EE 400000
#define GG 64
#define CAP 48

typedef unsigned short u16;
typedef unsigned char u8;
typedef long long i64;
typedef __attribute__((ext_vector_type(8))) short bf16x8;
typedef __attribute__((ext_vector_type(4))) float f32x4;
typedef __attribute__((ext_vector_type(2))) float f32x2;

__device__ __forceinline__ float b2f(u16 u) {
    unsigned int x = ((unsigned int)u) << 16;
    return __uint_as_float(x);
}
__device__ __forceinline__ u16 f2b(float f) {
    unsigned int x = __float_as_uint(f);
    unsigned int r = x + 0x7fffu + ((x >> 16) & 1u);
    return (u16)(r >> 16);
}
// fp8 e4m3 (OCP) via HW converts — internal tensors h1, h2pre, hL2, W2p only.
__device__ __forceinline__ u8 f2fp8(float f) {
    return (u8)(__builtin_amdgcn_cvt_pk_fp8_f32(f, f, 0, false) & 0xFF);
}
__device__ __forceinline__ f32x2 fp8x2_f32(unsigned int v, bool hi) {
    return hi ? __builtin_amdgcn_cvt_pk_f32_fp8(v, true)
              : __builtin_amdgcn_cvt_pk_f32_fp8(v, false);
}
__device__ __forceinline__ float wred_sum(float v) {
    #pragma unroll
    for (int o = 32; o; o >>= 1) v += __shfl_xor(v, o, 64);
    return v;
}
__device__ __forceinline__ float lrelu(float v) { return v > 0.f ? v : 0.2f * v; }

// ---- fused prep: init CSR + gstart + cvtW2(fp8) + prepW1 + zero pooled.
// grid 455: [0,196) init, 196 gstart, [197,453) cvtW2, 453 prepW1, 454 pooled.
__global__ void k_prep(const int* __restrict__ batch, int* __restrict__ deg,
                       int* __restrict__ col, int* __restrict__ gstart,
                       const float* __restrict__ W1, const float* __restrict__ as1,
                       const float* __restrict__ ad1, u16* __restrict__ W1p,
                       const float* __restrict__ W2, u8* __restrict__ W2p,
                       float* __restrict__ pooled) {
    __shared__ float asw[16][8];
    int b = blockIdx.x, t = threadIdx.x;
    if (b < 196) {
        int n = b * 256 + t;
        if (n < NN) { deg[n] = 1; col[(size_t)n * CAP] = n; }
    } else if (b == 196) {
        if (t <= GG) {
            int lo = 0, hi = NN;
            while (lo < hi) {
                int mid = (lo + hi) >> 1;
                if (batch[mid] < t) lo = mid + 1; else hi = mid;
            }
            gstart[t] = lo;
        }
    } else if (b < 453) {
        int idx = (b - 197) * 256 + t;   // 65536 total
        int j = idx & 7;
        int l = (idx >> 3) & 63;
        int ct = idx >> 9;
        int c = ct >> 3, tt = ct & 7;
        int k = c * 32 + (l >> 4) * 8 + j;
        int n = tt * 16 + (l & 15);
        W2p[idx] = f2fp8(W2[k * 128 + n]);
    } else if (b == 453) {
        int pair = t >> 1, half = t & 1;
        int k = pair >> 3, h = pair & 7;
        int hd = h & 3;
        const float* att = (h >= 4) ? ad1 : as1;
        float s = 0.f;
        int c0 = half * 64;
        for (int c = c0; c < c0 + 64; c++)
            s += W1[k * 512 + hd * 128 + c] * att[hd * 128 + c];
        s += __shfl_xor(s, 1, 64);
        if (half == 0) asw[k][h] = s;
        __syncthreads();
        for (int idx = t; idx < 33 * 64 * 8; idx += 256) {
            int j = idx & 7, l = (idx >> 3) & 63, tt = idx >> 9;
            int quad = l >> 4, m = l & 15;
            int k2 = quad * 8 + j;
            float v = 0.f;
            if (k2 < 16) {
                if (tt < 32) v = W1[k2 * 512 + tt * 16 + m];
                else if (m < 8) v = asw[k2][m];
            }
            W1p[idx] = f2b(v);
        }
    } else {
        for (int i = t; i < GG * 128; i += 256) pooled[i] = 0.f;
    }
}

// ---- bucket-append edges by dst
__global__ void k_edges(const int* __restrict__ ei, int* __restrict__ deg,
                        int* __restrict__ col) {
    int e = blockIdx.x * 256 + threadIdx.x;
    if (e < EE) {
        int s = ei[e];
        int d = ei[EE + e];
        int slot = atomicAdd(&deg[d], 1);
        if (slot < CAP) col[(size_t)d * CAP + slot] = s;
    }
}

// ---- layer1 linear via MFMA: [h1(fp8) | a_src1 | a_dst1] = x @ [W1 | asW]
__global__ __launch_bounds__(256) void k_gemm1(
    const float* __restrict__ x, const u16* __restrict__ W1p,
    u8* __restrict__ h1, float* __restrict__ a_src1, float* __restrict__ a_dst1) {
    int tid = threadIdx.x;
    int wave = tid >> 6, l = tid & 63;
    int quad = l >> 4, m = l & 15;
    int row0 = blockIdx.x * 64 + wave * 16;
    int arow = row0 + m;
    int arow_c = arow < NN ? arow : (NN - 1);
    bf16x8 af;
    if (quad < 2) {
        const float* xp = x + arow_c * 16 + quad * 8;
        float4 x0 = *(const float4*)(xp);
        float4 x1 = *(const float4*)(xp + 4);
        u16 tmp[8] = {f2b(x0.x), f2b(x0.y), f2b(x0.z), f2b(x0.w),
                      f2b(x1.x), f2b(x1.y), f2b(x1.z), f2b(x1.w)};
        af = *(bf16x8*)tmp;
    } else {
        af = (bf16x8){0, 0, 0, 0, 0, 0, 0, 0};
    }
    const u16* bp = W1p + l * 8;
    f32x4 acc[33];
    #pragma unroll
    for (int tt = 0; tt < 33; tt++) acc[tt] = (f32x4){0.f, 0.f, 0.f, 0.f};
    #pragma unroll
    for (int tt = 0; tt < 33; tt++) {
        bf16x8 bf = *(const bf16x8*)(bp + (size_t)tt * 512);
        acc[tt] = __builtin_amdgcn_mfma_f32_16x16x32_bf16(af, bf, acc[tt], 0, 0, 0);
    }
    #pragma unroll
    for (int r = 0; r < 4; r++) {
        int row = row0 + quad * 4 + r;
        if (row >= NN) continue;
        #pragma unroll
        for (int tt = 0; tt < 32; tt++)
            h1[(size_t)row * 512 + tt * 16 + m] = f2fp8(acc[tt][r]);
        float v = acc[32][r];
        if (m < 4) a_src1[row * 4 + m] = v;
        else if (m < 8) a_dst1[row * 4 + (m - 4)] = v;
    }
}

// ---- layer1 attention + aggregation: WAVE-PER-NODE, fused softmax in-wave,
// alpha in LDS (64 slots, unguarded writes, zeros beyond dg -> branchless
// 4-edges/iter gather loop). Output h2pre in fp8 (packed dword stores).
__global__ __launch_bounds__(256) void k_agg1(
    const int* __restrict__ deg, const int* __restrict__ col,
    const float* __restrict__ a_src1, const float* __restrict__ a_dst1,
    const u8* __restrict__ h1, const float* __restrict__ b1,
    u8* __restrict__ h2pre) {
    __shared__ float alphaS[4][64][4];
    int t = threadIdx.x;
    int wave = t >> 6, l = t & 63;
    int n = blockIdx.x * 4 + wave;
    if (n >= NN) return;
    int dg = min(deg[n], CAP);
    int sl = (l < dg) ? col[(size_t)n * CAP + l] : 0;
    float4 ad = *(const float4*)(a_dst1 + n * 4);
    float4 as = *(const float4*)(a_src1 + (size_t)sl * 4);
    float4 e;
    e.x = __expf(lrelu(as.x + ad.x)); e.y = __expf(lrelu(as.y + ad.y));
    e.z = __expf(lrelu(as.z + ad.z)); e.w = __expf(lrelu(as.w + ad.w));
    if (l >= dg) e = (float4){0.f, 0.f, 0.f, 0.f};
    float4 inv;
    inv.x = 1.0f / wred_sum(e.x);
    inv.y = 1.0f / wred_sum(e.y);
    inv.z = 1.0f / wred_sum(e.z);
    inv.w = 1.0f / wred_sum(e.w);
    {
        float4 a4;
        a4.x = e.x * inv.x; a4.y = e.y * inv.y;
        a4.z = e.z * inv.z; a4.w = e.w * inv.w;
        *(float4*)&alphaS[wave][l][0] = a4;   // zeros beyond dg
    }
    int h = l >> 4;
    const u8* hb = h1 + l * 8;
    f32x2 acc[4] = {{0.f, 0.f}, {0.f, 0.f}, {0.f, 0.f}, {0.f, 0.f}};
    int iters = (dg + 3) >> 2;
    for (int j = 0; j < iters; j++) {
        int e0 = 4 * j, e1 = 4 * j + 1, e2 = 4 * j + 2, e3 = 4 * j + 3;
        int s0 = __shfl(sl, e0), s1 = __shfl(sl, e1);
        int s2 = __shfl(sl, e2), s3 = __shfl(sl, e3);
        float a0 = alphaS[wave][e0][h], a1 = alphaS[wave][e1][h];
        float a2 = alphaS[wave][e2][h], a3 = alphaS[wave][e3][h];
        uint2 u0 = *(const uint2*)(hb + (size_t)s0 * 512);
        uint2 u1 = *(const uint2*)(hb + (size_t)s1 * 512);
        uint2 u2 = *(const uint2*)(hb + (size_t)s2 * 512);
        uint2 u3 = *(const uint2*)(hb + (size_t)s3 * 512);
        acc[0] += a0 * fp8x2_f32(u0.x, false);
        acc[1] += a0 * fp8x2_f32(u0.x, true);
        acc[2] += a0 * fp8x2_f32(u0.y, false);
        acc[3] += a0 * fp8x2_f32(u0.y, true);
        acc[0] += a1 * fp8x2_f32(u1.x, false);
        acc[1] += a1 * fp8x2_f32(u1.x, true);
        acc[2] += a1 * fp8x2_f32(u1.y, false);
        acc[3] += a1 * fp8x2_f32(u1.y, true);
        acc[0] += a2 * fp8x2_f32(u2.x, false);
        acc[1] += a2 * fp8x2_f32(u2.x, true);
        acc[2] += a2 * fp8x2_f32(u2.y, false);
        acc[3] += a2 * fp8x2_f32(u2.y, true);
        acc[0] += a3 * fp8x2_f32(u3.x, false);
        acc[1] += a3 * fp8x2_f32(u3.x, true);
        acc[2] += a3 * fp8x2_f32(u3.y, false);
        acc[3] += a3 * fp8x2_f32(u3.y, true);
    }
    int ch0 = l * 8;
    float4 bA = *(const float4*)(b1 + ch0);
    float4 bB = *(const float4*)(b1 + ch0 + 4);
    float av[8] = {acc[0].x, acc[0].y, acc[1].x, acc[1].y,
                   acc[2].x, acc[2].y, acc[3].x, acc[3].y};
    float bb[8] = {bA.x, bA.y, bA.z, bA.w, bB.x, bB.y, bB.z, bB.w};
    float v[8];
    #pragma unroll
    for (int k = 0; k < 8; k++) {
        float w = av[k] + bb[k];
        v[k] = w > 0.f ? w : __expf(w) - 1.0f;
    }
    unsigned int d0 = __builtin_amdgcn_cvt_pk_fp8_f32(v[0], v[1], 0, false);
    d0 = __builtin_amdgcn_cvt_pk_fp8_f32(v[2], v[3], d0, true);
    unsigned int d1 = __builtin_amdgcn_cvt_pk_fp8_f32(v[4], v[5], 0, false);
    d1 = __builtin_amdgcn_cvt_pk_fp8_f32(v[6], v[7], d1, true);
    uint2 ov; ov.x = d0; ov.y = d1;
    *(uint2*)(h2pre + (size_t)n * 512 + ch0) = ov;
}

// ---- layer2 linear via fp8 MFMA: hL2(fp8) = h2pre(fp8)@W2(fp8),
// fused a_src2/a_dst2. A/B frags are 8B loads (2 VGPRs).
__global__ __launch_bounds__(256) void k_gemm2(
    const u8* __restrict__ h2pre, const u8* __restrict__ W2p,
    const float* __restrict__ as2, const float* __restrict__ ad2,
    u8* __restrict__ hL2, float* __restrict__ a_src2, float* __restrict__ a_dst2) {
    int t = threadIdx.x;
    int wave = t >> 6, l = t & 63;
    int quad = l >> 4, m = l & 15;
    int row0 = blockIdx.x * 64 + wave * 16;
    int arow = row0 + m;
    int arow_c = arow < NN ? arow : (NN - 1);
    const u8* aptr = h2pre + (size_t)arow_c * 512 + quad * 8;
    const u8* bptr = W2p + l * 8;
    f32x4 acc[8];
    #pragma unroll
    for (int tt = 0; tt < 8; tt++) acc[tt] = (f32x4){0.f, 0.f, 0.f, 0.f};
    for (int c = 0; c < 16; c++) {
        i64 af = *(const i64*)(aptr + c * 32);
        #pragma unroll
        for (int tt = 0; tt < 8; tt++) {
            i64 bf = *(const i64*)(bptr + (size_t)(c * 8 + tt) * 512);
            acc[tt] = __builtin_amdgcn_mfma_f32_16x16x32_fp8_fp8(af, bf, acc[tt], 0, 0, 0);
        }
    }
    float asv[8], adv[8];
    #pragma unroll
    for (int tt = 0; tt < 8; tt++) {
        int colc = tt * 16 + m;
        asv[tt] = as2[colc];
        adv[tt] = ad2[colc];
    }
    #pragma unroll
    for (int r = 0; r < 4; r++) {
        int row = row0 + quad * 4 + r;
        bool ok = row < NN;
        float rs = 0.f, rd = 0.f;
        #pragma unroll
        for (int tt = 0; tt < 8; tt++) {
            float v = acc[tt][r];
            if (ok) hL2[(size_t)row * 128 + tt * 16 + m] = f2fp8(v);
            rs += v * asv[tt];
            rd += v * adv[tt];
        }
        #pragma unroll
        for (int o = 1; o < 16; o <<= 1) {
            rs += __shfl_xor(rs, o, 64);
            rd += __shfl_xor(rd, o, 64);
        }
        if (ok && m == 0) { a_src2[row] = rs; a_dst2[row] = rd; }
    }
}

// ---- layer2 attention + aggregation + POOL: WAVE-PER-NODE, fused softmax,
// branchless 4-edges/iter, block-combined atomicAdd into pooled.
__global__ __launch_bounds__(256) void k_agg2(
    const int* __restrict__ deg, const int* __restrict__ col,
    const float* __restrict__ a_src2, const float* __restrict__ a_dst2,
    const u8* __restrict__ hL2, const float* __restrict__ b2v,
    const int* __restrict__ batch, float* __restrict__ pooled) {
    __shared__ float red[4][128];
    __shared__ int gS[4];
    int t = threadIdx.x;
    int wave = t >> 6, l = t & 63;
    int n = blockIdx.x * 4 + wave;
    if (n >= NN) return;
    int dg = min(deg[n], CAP);
    int sl = (l < dg) ? col[(size_t)n * CAP + l] : 0;
    float ad = a_dst2[n];
    float e = (l < dg) ? __expf(lrelu(a_src2[sl] + ad)) : 0.f;
    float inv = 1.0f / wred_sum(e);
    float al = e * inv;                   // 0 beyond dg
    f32x2 acc = {0.f, 0.f};
    const u8* hb = hL2 + l * 2;
    int iters = (dg + 3) >> 2;
    for (int j = 0; j < iters; j++) {
        int e0 = 4 * j, e1 = 4 * j + 1, e2 = 4 * j + 2, e3 = 4 * j + 3;
        int s0 = __shfl(sl, e0), s1 = __shfl(sl, e1);
        int s2 = __shfl(sl, e2), s3 = __shfl(sl, e3);
        float a0 = __shfl(al, e0), a1 = __shfl(al, e1);
        float a2 = __shfl(al, e2), a3 = __shfl(al, e3);
        unsigned int u0 = *(const u16*)(hb + (size_t)s0 * 128);
        unsigned int u1 = *(const u16*)(hb + (size_t)s1 * 128);
        unsigned int u2 = *(const u16*)(hb + (size_t)s2 * 128);
        unsigned int u3 = *(const u16*)(hb + (size_t)s3 * 128);
        acc += a0 * fp8x2_f32(u0, false);
        acc += a1 * fp8x2_f32(u1, false);
        acc += a2 * fp8x2_f32(u2, false);
        acc += a3 * fp8x2_f32(u3, false);
    }
    float o0 = acc.x + b2v[2 * l];     o0 = o0 > 0.f ? o0 : __expf(o0) - 1.0f;
    float o1 = acc.y + b2v[2 * l + 1]; o1 = o1 > 0.f ? o1 : __expf(o1) - 1.0f;
    red[wave][2 * l] = o0;
    red[wave][2 * l + 1] = o1;
    if (l == 0) gS[wave] = batch[n];
    __syncthreads();
    if (t < 128) {
        int g0 = gS[0];
        if (gS[1] == g0 && gS[2] == g0 && gS[3] == g0) {
            float s = red[0][t] + red[1][t] + red[2][t] + red[3][t];
            atomicAdd(&pooled[g0 * 128 + t], s);
        } else {
            #pragma unroll
            for (int w = 0; w < 4; w++)
                atomicAdd(&pooled[gS[w] * 128 + t], red[w][t]);
        }
    }
}

// ---- graph MLP + classifier (pooled holds per-graph SUMS)
__global__ __launch_bounds__(128) void k_head(
    const int* __restrict__ gstart, const float* __restrict__ pooled,
    const float* __restrict__ gfeat,
    const float* __restrict__ Wg1, const float* __restrict__ bg1,
    const float* __restrict__ Wg2, const float* __restrict__ bg2,
    const float* __restrict__ Wc1, const float* __restrict__ bc1,
    const float* __restrict__ Wc2, const float* __restrict__ bc2,
    float* __restrict__ out) {
    __shared__ float z[160];
    __shared__ float hg[32];
    __shared__ float c1b[128];
    int g = blockIdx.x, t = threadIdx.x;
    float cntf = (float)(gstart[g + 1] - gstart[g]);
    z[t] = pooled[g * 128 + t] / fmaxf(cntf, 1.0f);
    if (t < 32) {
        float a = bg1[t];
        for (int i = 0; i < 10; i++) a += gfeat[g * 10 + i] * Wg1[i * 32 + t];
        hg[t] = fmaxf(a, 0.f);
    }
    __syncthreads();
    if (t < 32) {
        float a = bg2[t];
        for (int i = 0; i < 32; i++) a += hg[i] * Wg2[i * 32 + t];
        z[128 + t] = a;
    }
    __syncthreads();
    float a = bc1[t];
    for (int i = 0; i < 160; i++) a += z[i] * Wc1[i * 128 + t];
    c1b[t] = fmaxf(a, 0.f);
    __syncthreads();
    if (t < 6) {
        float o = bc2[t];
        for (int i = 0; i < 128; i++) o += c1b[i] * Wc2[i * 6 + t];
        out[g * 6 + t] = o;
    }
}

extern "C" void kernel_launch(void* const* d_in, const int* in_sizes, int n_in,
                              void* d_out, int out_size, void* d_ws, size_t ws_size,
                              hipStream_t stream) {
    const float* x     = (const float*)d_in[0];
    const int*   ei    = (const int*)d_in[1];
    const int*   batch = (const int*)d_in[2];
    const float* gfeat = (const float*)d_in[3];
    const float* W1    = (const float*)d_in[4];
    const float* as1   = (const float*)d_in[5];
    const float* ad1   = (const float*)d_in[6];
    const float* b1    = (const float*)d_in[7];
    const float* W2    = (const float*)d_in[8];
    const float* as2   = (const float*)d_in[9];
    const float* ad2   = (const float*)d_in[10];
    const float* b2    = (const float*)d_in[11];
    const float* Wg1   = (const float*)d_in[12];
    const float* bg1   = (const float*)d_in[13];
    const float* Wg2   = (const float*)d_in[14];
    const float* bg2   = (const float*)d_in[15];
    const float* Wc1   = (const float*)d_in[16];
    const float* bc1   = (const float*)d_in[17];
    const float* Wc2   = (const float*)d_in[18];
    const float* bc2   = (const float*)d_in[19];
    float* out = (float*)d_out;

    size_t off = 0;
    char* base = (char*)d_ws;
    auto take = [&](size_t nbytes) -> char* {
        char* p = base + off;
        off = (off + nbytes + 255) & ~(size_t)255;
        return p;
    };
    u8*    h1     = (u8*)take((size_t)NN * 512);
    u8*    h2pre  = (u8*)take((size_t)NN * 512);
    u8*    hL2    = (u8*)take((size_t)NN * 128);
    float* a_src1 = (float*)take((size_t)NN * 4 * 4);
    float* a_dst1 = (float*)take((size_t)NN * 4 * 4);
    float* a_src2 = (float*)take((size_t)NN * 4);
    float* a_dst2 = (float*)take((size_t)NN * 4);
    int*   deg    = (int*)take((size_t)NN * 4);
    int*   col    = (int*)take((size_t)NN * CAP * 4);
    float* pooled = (float*)take(GG * 128 * 4);
    int*   gstart = (int*)take((GG + 1) * 4);
    u8*    W2p    = (u8*)take((size_t)512 * 128);
    u16*   W1p    = (u16*)take((size_t)33 * 64 * 8 * 2);
    (void)ws_size; (void)in_sizes; (void)n_in; (void)out_size;

    k_prep<<<455, 256, 0, stream>>>(batch, deg, col, gstart, W1, as1, ad1, W1p,
                                    W2, W2p, pooled);
    k_edges<<<(EE + 255) / 256, 256, 0, stream>>>(ei, deg, col);
    k_gemm1<<<(NN + 63) / 64, 256, 0, stream>>>(x, W1p, h1, a_src1, a_dst1);
    k_agg1<<<(NN + 3) / 4, 256, 0, stream>>>(deg, col, a_src1, a_dst1, h1, b1, h2pre);
    k_gemm2<<<(NN + 63) / 64, 256, 0, stream>>>(h2pre, W2p, as2, ad2, hL2, a_src2, a_dst2);
    k_agg2<<<(NN + 3) / 4, 256, 0, stream>>>(deg, col, a_src2, a_dst2, hL2, b2,
                                             batch, pooled);
    k_head<<<GG, 128, 0, stream>>>(gstart, pooled, gfeat, Wg1, bg1, Wg2, bg2,
                                   Wc1, bc1, Wc2, bc2, out);
}